// Round 1
// baseline (2265.702 us; speedup 1.0000x reference)
//
#include <hip/hip_runtime.h>
#include <math.h>

#define N_NODES 50000
#define N_EDGES 400000
#define HD 32
#define N_ET 8

__device__ inline void fma4(float4& a, float s, const float4 w) {
    a.x = fmaf(s, w.x, a.x);
    a.y = fmaf(s, w.y, a.y);
    a.z = fmaf(s, w.z, a.z);
    a.w = fmaf(s, w.w, a.w);
}

// Transform: v = use_agg ? (x+agg)*0.5 : x ; cur = v ; Y[t][n] = v @ W_t for all t.
template <int USE_AGG>
__global__ __launch_bounds__(256) void k_transform(
    const float* __restrict__ xin, const float* __restrict__ aggin,
    const float* __restrict__ param, float* __restrict__ cur,
    float* __restrict__ Y)
{
    int n = blockIdx.x * blockDim.x + threadIdx.x;
    if (n >= N_NODES) return;
    const size_t base = (size_t)n * HD;

    float x[HD];
    #pragma unroll
    for (int q = 0; q < 8; ++q) {
        float4 v = *(const float4*)(xin + base + q * 4);
        if (USE_AGG) {
            float4 a = *(const float4*)(aggin + base + q * 4);
            v.x = (v.x + a.x) * 0.5f;
            v.y = (v.y + a.y) * 0.5f;
            v.z = (v.z + a.z) * 0.5f;
            v.w = (v.w + a.w) * 0.5f;
        }
        x[q * 4 + 0] = v.x; x[q * 4 + 1] = v.y;
        x[q * 4 + 2] = v.z; x[q * 4 + 3] = v.w;
        *(float4*)(cur + base + q * 4) = v;
    }

    for (int t = 0; t < N_ET; ++t) {            // rolled: weight offsets stay uniform -> s_load
        const float* W = param + t * (HD * HD);
        float4 acc[8];
        #pragma unroll
        for (int q = 0; q < 8; ++q) acc[q] = make_float4(0.f, 0.f, 0.f, 0.f);
        #pragma unroll
        for (int i = 0; i < HD; ++i) {
            float xi = x[i];
            #pragma unroll
            for (int q = 0; q < 8; ++q)
                fma4(acc[q], xi, *(const float4*)(W + i * HD + q * 4));
        }
        float* yo = Y + (size_t)t * N_NODES * HD + base;
        #pragma unroll
        for (int q = 0; q < 8; ++q) *(float4*)(yo + q * 4) = acc[q];
    }
}

// Edge scatter: agg[dst] += Y[pid][src]  (pure gather + fp32 atomics)
__global__ __launch_bounds__(256) void k_edge(
    const int* __restrict__ src, const int* __restrict__ dst,
    const int* __restrict__ pid, const float* __restrict__ Y,
    float* __restrict__ agg)
{
    int e = blockIdx.x * blockDim.x + threadIdx.x;
    if (e >= N_EDGES) return;
    int s = src[e], d = dst[e], t = pid[e];
    const float* yp = Y + ((size_t)t * N_NODES + s) * HD;
    float4 m[8];
    #pragma unroll
    for (int q = 0; q < 8; ++q) m[q] = *(const float4*)(yp + q * 4);
    float* ap = agg + (size_t)d * HD;
    #pragma unroll
    for (int q = 0; q < 8; ++q) {
        unsafeAtomicAdd(ap + q * 4 + 0, m[q].x);
        unsafeAtomicAdd(ap + q * 4 + 1, m[q].y);
        unsafeAtomicAdd(ap + q * 4 + 2, m[q].z);
        unsafeAtomicAdd(ap + q * 4 + 3, m[q].w);
    }
}

// Final: v=(cur+agg)*0.5 ; L2-normalize ; MLP 32->64 tanh ->64 tanh ->1 ; sigmoid
__global__ __launch_bounds__(128) void k_final(
    const float* __restrict__ cur, const float* __restrict__ agg,
    const float* __restrict__ w1, const float* __restrict__ b1,
    const float* __restrict__ w2, const float* __restrict__ b2,
    const float* __restrict__ w3, const float* __restrict__ b3,
    float* __restrict__ out)
{
    __shared__ float xs[128 * 65];               // private row per thread, pad 65 -> conflict-free
    int n = blockIdx.x * blockDim.x + threadIdx.x;
    if (n >= N_NODES) return;
    float* row = xs + threadIdx.x * 65;
    const size_t base = (size_t)n * HD;

    float ss = 0.f;
    #pragma unroll
    for (int q = 0; q < 8; ++q) {
        float4 a = *(const float4*)(cur + base + q * 4);
        float4 g = *(const float4*)(agg + base + q * 4);
        a.x = (a.x + g.x) * 0.5f; a.y = (a.y + g.y) * 0.5f;
        a.z = (a.z + g.z) * 0.5f; a.w = (a.w + g.w) * 0.5f;
        ss += a.x * a.x + a.y * a.y + a.z * a.z + a.w * a.w;
        row[q * 4 + 0] = a.x; row[q * 4 + 1] = a.y;
        row[q * 4 + 2] = a.z; row[q * 4 + 3] = a.w;
    }
    float rn = 1.0f / fmaxf(sqrtf(ss), 1e-12f);

    // layer 1: 32 -> 64
    float4 h[16];
    #pragma unroll
    for (int q = 0; q < 16; ++q) h[q] = *(const float4*)(b1 + q * 4);
    for (int i = 0; i < HD; ++i) {               // rolled: w1 offsets uniform -> s_load
        float xi = row[i] * rn;
        #pragma unroll
        for (int q = 0; q < 16; ++q)
            fma4(h[q], xi, *(const float4*)(w1 + i * 64 + q * 4));
    }
    #pragma unroll
    for (int q = 0; q < 16; ++q) {
        row[q * 4 + 0] = tanhf(h[q].x); row[q * 4 + 1] = tanhf(h[q].y);
        row[q * 4 + 2] = tanhf(h[q].z); row[q * 4 + 3] = tanhf(h[q].w);
    }

    // layer 2: 64 -> 64
    float4 h2[16];
    #pragma unroll
    for (int q = 0; q < 16; ++q) h2[q] = *(const float4*)(b2 + q * 4);
    for (int i = 0; i < 64; ++i) {               // rolled
        float xi = row[i];
        #pragma unroll
        for (int q = 0; q < 16; ++q)
            fma4(h2[q], xi, *(const float4*)(w2 + i * 64 + q * 4));
    }

    // layer 3: 64 -> 1, tanh applied on h2 components
    float lg = b3[0];
    #pragma unroll
    for (int q = 0; q < 16; ++q) {
        float4 w = *(const float4*)(w3 + q * 4);
        lg = fmaf(tanhf(h2[q].x), w.x, lg);
        lg = fmaf(tanhf(h2[q].y), w.y, lg);
        lg = fmaf(tanhf(h2[q].z), w.z, lg);
        lg = fmaf(tanhf(h2[q].w), w.w, lg);
    }
    out[n] = 1.0f / (1.0f + expf(-lg));
}

extern "C" void kernel_launch(void* const* d_in, const int* in_sizes, int n_in,
                              void* d_out, int out_size, void* d_ws, size_t ws_size,
                              hipStream_t stream) {
    const float* feature = (const float*)d_in[0];
    const float* param   = (const float*)d_in[1];
    const float* w1      = (const float*)d_in[2];
    const float* b1      = (const float*)d_in[3];
    const float* w2      = (const float*)d_in[4];
    const float* b2      = (const float*)d_in[5];
    const float* w3      = (const float*)d_in[6];
    const float* b3      = (const float*)d_in[7];
    const int*   src     = (const int*)d_in[8];
    const int*   dst     = (const int*)d_in[9];
    const int*   pid     = (const int*)d_in[10];
    float* out = (float*)d_out;

    const size_t Y_BYTES   = (size_t)N_ET * N_NODES * HD * sizeof(float);   // 51.2 MB
    const size_t NH_BYTES  = (size_t)N_NODES * HD * sizeof(float);          // 6.4 MB
    float* Y   = (float*)d_ws;
    float* cur = (float*)((char*)d_ws + Y_BYTES);
    float* agg = (float*)((char*)d_ws + Y_BYTES + NH_BYTES);

    const int TB = 256;
    const int gT = (N_NODES + TB - 1) / TB;
    const int gE = (N_EDGES + TB - 1) / TB;
    const int gF = (N_NODES + 127) / 128;

    // layer 1
    hipMemsetAsync(agg, 0, NH_BYTES, stream);
    k_transform<0><<<gT, TB, 0, stream>>>(feature, nullptr, param, cur, Y);
    k_edge<<<gE, TB, 0, stream>>>(src, dst, pid, Y, agg);
    // layer 2
    k_transform<1><<<gT, TB, 0, stream>>>(cur, agg, param, cur, Y);
    hipMemsetAsync(agg, 0, NH_BYTES, stream);
    k_edge<<<gE, TB, 0, stream>>>(src, dst, pid, Y, agg);
    // layer 3
    k_transform<1><<<gT, TB, 0, stream>>>(cur, agg, param, cur, Y);
    hipMemsetAsync(agg, 0, NH_BYTES, stream);
    k_edge<<<gE, TB, 0, stream>>>(src, dst, pid, Y, agg);
    // combine + normalize + MLP + sigmoid
    k_final<<<gF, 128, 0, stream>>>(cur, agg, w1, b1, w2, b2, w3, b3, out);
}

// Round 2
// 316.280 us; speedup vs baseline: 7.1636x; 7.1636x over previous
//
#include <hip/hip_runtime.h>
#include <math.h>

#define N_NODES 50000
#define N_EDGES 400000
#define HD 32
#define N_ET 8
#define CAP 64   // ELL capacity; Poisson(8) max degree ~30, P(>=64) ~ 1e-40

__device__ inline void fma4(float4& a, float s, const float4 w) {
    a.x = fmaf(s, w.x, a.x);
    a.y = fmaf(s, w.y, a.y);
    a.z = fmaf(s, w.z, a.z);
    a.w = fmaf(s, w.w, a.w);
}

// Build ELL adjacency keyed by dst: payload[d][k] = pid*N_NODES + src
__global__ __launch_bounds__(256) void k_count(
    const int* __restrict__ src, const int* __restrict__ dst,
    const int* __restrict__ pid, int* __restrict__ deg,
    int* __restrict__ payload)
{
    int e = blockIdx.x * blockDim.x + threadIdx.x;
    if (e >= N_EDGES) return;
    int d = dst[e];
    int pos = atomicAdd(&deg[d], 1);
    if (pos < CAP) payload[d * CAP + pos] = pid[e] * N_NODES + src[e];
}

// Transform: v = use_agg ? (x+agg)*0.5 : x ; cur = v ; Y[t][n] = v @ W_t for all t.
template <int USE_AGG>
__global__ __launch_bounds__(256) void k_transform(
    const float* __restrict__ xin, const float* __restrict__ aggin,
    const float* __restrict__ param, float* __restrict__ cur,
    float* __restrict__ Y)
{
    int n = blockIdx.x * blockDim.x + threadIdx.x;
    if (n >= N_NODES) return;
    const size_t base = (size_t)n * HD;

    float x[HD];
    #pragma unroll
    for (int q = 0; q < 8; ++q) {
        float4 v = *(const float4*)(xin + base + q * 4);
        if (USE_AGG) {
            float4 a = *(const float4*)(aggin + base + q * 4);
            v.x = (v.x + a.x) * 0.5f;
            v.y = (v.y + a.y) * 0.5f;
            v.z = (v.z + a.z) * 0.5f;
            v.w = (v.w + a.w) * 0.5f;
        }
        x[q * 4 + 0] = v.x; x[q * 4 + 1] = v.y;
        x[q * 4 + 2] = v.z; x[q * 4 + 3] = v.w;
        *(float4*)(cur + base + q * 4) = v;
    }

    for (int t = 0; t < N_ET; ++t) {            // rolled: weight offsets stay uniform -> s_load
        const float* W = param + t * (HD * HD);
        float4 acc[8];
        #pragma unroll
        for (int q = 0; q < 8; ++q) acc[q] = make_float4(0.f, 0.f, 0.f, 0.f);
        #pragma unroll
        for (int i = 0; i < HD; ++i) {
            float xi = x[i];
            #pragma unroll
            for (int q = 0; q < 8; ++q)
                fma4(acc[q], xi, *(const float4*)(W + i * HD + q * 4));
        }
        float* yo = Y + (size_t)t * N_NODES * HD + base;
        #pragma unroll
        for (int q = 0; q < 8; ++q) *(float4*)(yo + q * 4) = acc[q];
    }
}

// Gather: agg[n] = sum over incoming edges of Y[pid][src].
// 8 lanes per node; lane sl owns 16B slice -> 8 lanes read one contiguous 128B.
__global__ __launch_bounds__(256) void k_gather(
    const int* __restrict__ deg, const int* __restrict__ payload,
    const float* __restrict__ Y, float* __restrict__ agg)
{
    int tid = blockIdx.x * blockDim.x + threadIdx.x;
    int node = tid >> 3, sl = tid & 7;
    if (node >= N_NODES) return;
    int d = deg[node];
    if (d > CAP) d = CAP;
    const int* pl = payload + node * CAP;
    float4 acc = make_float4(0.f, 0.f, 0.f, 0.f);
    for (int k = 0; k < d; ++k) {
        int c = pl[k];                                   // broadcast across the 8-lane group
        const float4 v = *(const float4*)(Y + (size_t)c * HD + sl * 4);
        acc.x += v.x; acc.y += v.y; acc.z += v.z; acc.w += v.w;
    }
    *(float4*)(agg + (size_t)node * HD + sl * 4) = acc;
}

// Final: v=(cur+agg)*0.5 ; L2-normalize ; MLP 32->64 tanh ->64 tanh ->1 ; sigmoid
__global__ __launch_bounds__(128) void k_final(
    const float* __restrict__ cur, const float* __restrict__ agg,
    const float* __restrict__ w1, const float* __restrict__ b1,
    const float* __restrict__ w2, const float* __restrict__ b2,
    const float* __restrict__ w3, const float* __restrict__ b3,
    float* __restrict__ out)
{
    __shared__ float xs[128 * 65];               // private row per thread, pad 65 -> conflict-free
    int n = blockIdx.x * blockDim.x + threadIdx.x;
    if (n >= N_NODES) return;
    float* row = xs + threadIdx.x * 65;
    const size_t base = (size_t)n * HD;

    float ss = 0.f;
    #pragma unroll
    for (int q = 0; q < 8; ++q) {
        float4 a = *(const float4*)(cur + base + q * 4);
        float4 g = *(const float4*)(agg + base + q * 4);
        a.x = (a.x + g.x) * 0.5f; a.y = (a.y + g.y) * 0.5f;
        a.z = (a.z + g.z) * 0.5f; a.w = (a.w + g.w) * 0.5f;
        ss += a.x * a.x + a.y * a.y + a.z * a.z + a.w * a.w;
        row[q * 4 + 0] = a.x; row[q * 4 + 1] = a.y;
        row[q * 4 + 2] = a.z; row[q * 4 + 3] = a.w;
    }
    float rn = 1.0f / fmaxf(sqrtf(ss), 1e-12f);

    // layer 1: 32 -> 64
    float4 h[16];
    #pragma unroll
    for (int q = 0; q < 16; ++q) h[q] = *(const float4*)(b1 + q * 4);
    for (int i = 0; i < HD; ++i) {               // rolled: w1 offsets uniform -> s_load
        float xi = row[i] * rn;
        #pragma unroll
        for (int q = 0; q < 16; ++q)
            fma4(h[q], xi, *(const float4*)(w1 + i * 64 + q * 4));
    }
    #pragma unroll
    for (int q = 0; q < 16; ++q) {
        row[q * 4 + 0] = tanhf(h[q].x); row[q * 4 + 1] = tanhf(h[q].y);
        row[q * 4 + 2] = tanhf(h[q].z); row[q * 4 + 3] = tanhf(h[q].w);
    }

    // layer 2: 64 -> 64
    float4 h2[16];
    #pragma unroll
    for (int q = 0; q < 16; ++q) h2[q] = *(const float4*)(b2 + q * 4);
    for (int i = 0; i < 64; ++i) {               // rolled
        float xi = row[i];
        #pragma unroll
        for (int q = 0; q < 16; ++q)
            fma4(h2[q], xi, *(const float4*)(w2 + i * 64 + q * 4));
    }

    // layer 3: 64 -> 1, tanh applied on h2 components
    float lg = b3[0];
    #pragma unroll
    for (int q = 0; q < 16; ++q) {
        float4 w = *(const float4*)(w3 + q * 4);
        lg = fmaf(tanhf(h2[q].x), w.x, lg);
        lg = fmaf(tanhf(h2[q].y), w.y, lg);
        lg = fmaf(tanhf(h2[q].z), w.z, lg);
        lg = fmaf(tanhf(h2[q].w), w.w, lg);
    }
    out[n] = 1.0f / (1.0f + expf(-lg));
}

extern "C" void kernel_launch(void* const* d_in, const int* in_sizes, int n_in,
                              void* d_out, int out_size, void* d_ws, size_t ws_size,
                              hipStream_t stream) {
    const float* feature = (const float*)d_in[0];
    const float* param   = (const float*)d_in[1];
    const float* w1      = (const float*)d_in[2];
    const float* b1      = (const float*)d_in[3];
    const float* w2      = (const float*)d_in[4];
    const float* b2      = (const float*)d_in[5];
    const float* w3      = (const float*)d_in[6];
    const float* b3      = (const float*)d_in[7];
    const int*   src     = (const int*)d_in[8];
    const int*   dst     = (const int*)d_in[9];
    const int*   pid     = (const int*)d_in[10];
    float* out = (float*)d_out;

    const size_t Y_BYTES   = (size_t)N_ET * N_NODES * HD * sizeof(float);   // 51.2 MB
    const size_t NH_BYTES  = (size_t)N_NODES * HD * sizeof(float);          // 6.4 MB
    const size_t DEG_BYTES = (size_t)N_NODES * sizeof(int);                 // 0.2 MB
    char* p = (char*)d_ws;
    float* Y       = (float*)p;            p += Y_BYTES;
    float* cur     = (float*)p;            p += NH_BYTES;
    float* agg     = (float*)p;            p += NH_BYTES;
    int*   deg     = (int*)p;              p += DEG_BYTES;
    int*   payload = (int*)p;              // 50K * 64 * 4B = 12.8 MB

    const int TB = 256;
    const int gT = (N_NODES + TB - 1) / TB;
    const int gE = (N_EDGES + TB - 1) / TB;
    const int gG = (N_NODES * 8 + TB - 1) / TB;
    const int gF = (N_NODES + 127) / 128;

    // Build dst-keyed ELL adjacency (int atomics only, once per launch)
    hipMemsetAsync(deg, 0, DEG_BYTES, stream);
    k_count<<<gE, TB, 0, stream>>>(src, dst, pid, deg, payload);

    // layer 1
    k_transform<0><<<gT, TB, 0, stream>>>(feature, nullptr, param, cur, Y);
    k_gather<<<gG, TB, 0, stream>>>(deg, payload, Y, agg);
    // layer 2
    k_transform<1><<<gT, TB, 0, stream>>>(cur, agg, param, cur, Y);
    k_gather<<<gG, TB, 0, stream>>>(deg, payload, Y, agg);
    // layer 3
    k_transform<1><<<gT, TB, 0, stream>>>(cur, agg, param, cur, Y);
    k_gather<<<gG, TB, 0, stream>>>(deg, payload, Y, agg);
    // combine + normalize + MLP + sigmoid
    k_final<<<gF, 128, 0, stream>>>(cur, agg, w1, b1, w2, b2, w3, b3, out);
}

// Round 3
// 266.449 us; speedup vs baseline: 8.5033x; 1.1870x over previous
//
#include <hip/hip_runtime.h>
#include <math.h>

#define N_NODES 50000
#define N_EDGES 400000
#define HD 32
#define N_ET 8
#define CAP 64   // ELL capacity; Poisson(8) max degree ~30, P(>=64) ~ 1e-40

__device__ inline void fma4(float4& a, float s, const float4 w) {
    a.x = fmaf(s, w.x, a.x);
    a.y = fmaf(s, w.y, a.y);
    a.z = fmaf(s, w.z, a.z);
    a.w = fmaf(s, w.w, a.w);
}

// Build ELL adjacency keyed by dst: payload[d][k] = pid*N_NODES + src
__global__ __launch_bounds__(256) void k_count(
    const int* __restrict__ src, const int* __restrict__ dst,
    const int* __restrict__ pid, int* __restrict__ deg,
    int* __restrict__ payload)
{
    int e = blockIdx.x * blockDim.x + threadIdx.x;
    if (e >= N_EDGES) return;
    int d = dst[e];
    int pos = atomicAdd(&deg[d], 1);
    if (pos < CAP) payload[d * CAP + pos] = pid[e] * N_NODES + src[e];
}

// Transform: Y[t][n] = x[n] @ W_t.  One edge-type per block (blockIdx.y) so the
// weight pointer is wave-uniform -> s_load; one node per thread.
__global__ __launch_bounds__(256) void k_transform(
    const float* __restrict__ xin, const float* __restrict__ param,
    float* __restrict__ Y)
{
    int n = blockIdx.x * blockDim.x + threadIdx.x;
    if (n >= N_NODES) return;
    const int t = blockIdx.y;
    const size_t base = (size_t)n * HD;
    const float* W = param + t * (HD * HD);

    float x[HD];
    #pragma unroll
    for (int q = 0; q < 8; ++q) {
        float4 v = *(const float4*)(xin + base + q * 4);
        x[q * 4 + 0] = v.x; x[q * 4 + 1] = v.y;
        x[q * 4 + 2] = v.z; x[q * 4 + 3] = v.w;
    }

    float4 acc[8];
    #pragma unroll
    for (int q = 0; q < 8; ++q) acc[q] = make_float4(0.f, 0.f, 0.f, 0.f);
    #pragma unroll
    for (int i = 0; i < HD; ++i) {
        float xi = x[i];
        #pragma unroll
        for (int q = 0; q < 8; ++q)
            fma4(acc[q], xi, *(const float4*)(W + i * HD + q * 4));
    }
    float* yo = Y + (size_t)t * N_NODES * HD + base;
    #pragma unroll
    for (int q = 0; q < 8; ++q) *(float4*)(yo + q * 4) = acc[q];
}

// Gather + combine: xout[n] = (xin[n] + sum_{e in in(n)} Y[pid_e][src_e]) * 0.5
// 8 lanes per node; lane sl owns a 16B slice -> group reads contiguous 128B.
__global__ __launch_bounds__(256) void k_gather(
    const int* __restrict__ deg, const int* __restrict__ payload,
    const float* __restrict__ Y, const float* __restrict__ xin,
    float* __restrict__ xout)
{
    int tid = blockIdx.x * blockDim.x + threadIdx.x;
    int node = tid >> 3, sl = tid & 7;
    if (node >= N_NODES) return;
    int d = deg[node];
    if (d > CAP) d = CAP;
    const int* pl = payload + node * CAP;
    float4 acc = make_float4(0.f, 0.f, 0.f, 0.f);
    for (int k = 0; k < d; ++k) {
        int c = pl[k];                                   // broadcast across the 8-lane group
        const float4 v = *(const float4*)(Y + (size_t)c * HD + sl * 4);
        acc.x += v.x; acc.y += v.y; acc.z += v.z; acc.w += v.w;
    }
    const size_t off = (size_t)node * HD + sl * 4;
    float4 x = *(const float4*)(xin + off);
    x.x = (x.x + acc.x) * 0.5f;
    x.y = (x.y + acc.y) * 0.5f;
    x.z = (x.z + acc.z) * 0.5f;
    x.w = (x.w + acc.w) * 0.5f;
    *(float4*)(xout + off) = x;
}

// Final: L2-normalize ; MLP 32->64 tanh ->64 tanh ->1 ; sigmoid
__global__ __launch_bounds__(128) void k_final(
    const float* __restrict__ cur,
    const float* __restrict__ w1, const float* __restrict__ b1,
    const float* __restrict__ w2, const float* __restrict__ b2,
    const float* __restrict__ w3, const float* __restrict__ b3,
    float* __restrict__ out)
{
    __shared__ float xs[128 * 65];               // private row per thread, pad 65 -> conflict-free
    int n = blockIdx.x * blockDim.x + threadIdx.x;
    if (n >= N_NODES) return;
    float* row = xs + threadIdx.x * 65;
    const size_t base = (size_t)n * HD;

    float ss = 0.f;
    #pragma unroll
    for (int q = 0; q < 8; ++q) {
        float4 a = *(const float4*)(cur + base + q * 4);
        ss += a.x * a.x + a.y * a.y + a.z * a.z + a.w * a.w;
        row[q * 4 + 0] = a.x; row[q * 4 + 1] = a.y;
        row[q * 4 + 2] = a.z; row[q * 4 + 3] = a.w;
    }
    float rn = 1.0f / fmaxf(sqrtf(ss), 1e-12f);

    // layer 1: 32 -> 64
    float4 h[16];
    #pragma unroll
    for (int q = 0; q < 16; ++q) h[q] = *(const float4*)(b1 + q * 4);
    for (int i = 0; i < HD; ++i) {               // rolled: w1 offsets uniform -> s_load
        float xi = row[i] * rn;
        #pragma unroll
        for (int q = 0; q < 16; ++q)
            fma4(h[q], xi, *(const float4*)(w1 + i * 64 + q * 4));
    }
    #pragma unroll
    for (int q = 0; q < 16; ++q) {
        row[q * 4 + 0] = tanhf(h[q].x); row[q * 4 + 1] = tanhf(h[q].y);
        row[q * 4 + 2] = tanhf(h[q].z); row[q * 4 + 3] = tanhf(h[q].w);
    }

    // layer 2: 64 -> 64
    float4 h2[16];
    #pragma unroll
    for (int q = 0; q < 16; ++q) h2[q] = *(const float4*)(b2 + q * 4);
    for (int i = 0; i < 64; ++i) {               // rolled
        float xi = row[i];
        #pragma unroll
        for (int q = 0; q < 16; ++q)
            fma4(h2[q], xi, *(const float4*)(w2 + i * 64 + q * 4));
    }

    // layer 3: 64 -> 1, tanh applied on h2 components
    float lg = b3[0];
    #pragma unroll
    for (int q = 0; q < 16; ++q) {
        float4 w = *(const float4*)(w3 + q * 4);
        lg = fmaf(tanhf(h2[q].x), w.x, lg);
        lg = fmaf(tanhf(h2[q].y), w.y, lg);
        lg = fmaf(tanhf(h2[q].z), w.z, lg);
        lg = fmaf(tanhf(h2[q].w), w.w, lg);
    }
    out[n] = 1.0f / (1.0f + expf(-lg));
}

extern "C" void kernel_launch(void* const* d_in, const int* in_sizes, int n_in,
                              void* d_out, int out_size, void* d_ws, size_t ws_size,
                              hipStream_t stream) {
    const float* feature = (const float*)d_in[0];
    const float* param   = (const float*)d_in[1];
    const float* w1      = (const float*)d_in[2];
    const float* b1      = (const float*)d_in[3];
    const float* w2      = (const float*)d_in[4];
    const float* b2      = (const float*)d_in[5];
    const float* w3      = (const float*)d_in[6];
    const float* b3      = (const float*)d_in[7];
    const int*   src     = (const int*)d_in[8];
    const int*   dst     = (const int*)d_in[9];
    const int*   pid     = (const int*)d_in[10];
    float* out = (float*)d_out;

    const size_t Y_BYTES   = (size_t)N_ET * N_NODES * HD * sizeof(float);   // 51.2 MB
    const size_t NH_BYTES  = (size_t)N_NODES * HD * sizeof(float);          // 6.4 MB
    const size_t DEG_BYTES = (size_t)N_NODES * sizeof(int);                 // 0.2 MB
    char* p = (char*)d_ws;
    float* Y       = (float*)p;            p += Y_BYTES;
    float* cur     = (float*)p;            p += NH_BYTES;
    int*   deg     = (int*)p;              p += DEG_BYTES;
    int*   payload = (int*)p;              // 50K * 64 * 4B = 12.8 MB

    const int TB = 256;
    const int gT = (N_NODES + TB - 1) / TB;     // 196
    const int gE = (N_EDGES + TB - 1) / TB;
    const int gG = (N_NODES * 8 + TB - 1) / TB;
    const int gF = (N_NODES + 127) / 128;
    dim3 gridT(gT, N_ET);                       // 1568 blocks, t uniform per block

    // Build dst-keyed ELL adjacency (int atomics only, once per launch)
    hipMemsetAsync(deg, 0, DEG_BYTES, stream);
    k_count<<<gE, TB, 0, stream>>>(src, dst, pid, deg, payload);

    // layer 1
    k_transform<<<gridT, TB, 0, stream>>>(feature, param, Y);
    k_gather<<<gG, TB, 0, stream>>>(deg, payload, Y, feature, cur);
    // layer 2
    k_transform<<<gridT, TB, 0, stream>>>(cur, param, Y);
    k_gather<<<gG, TB, 0, stream>>>(deg, payload, Y, cur, cur);
    // layer 3
    k_transform<<<gridT, TB, 0, stream>>>(cur, param, Y);
    k_gather<<<gG, TB, 0, stream>>>(deg, payload, Y, cur, cur);
    // normalize + MLP + sigmoid
    k_final<<<gF, 128, 0, stream>>>(cur, w1, b1, w2, b2, w3, b3, out);
}